// Round 1
// baseline (371.238 us; speedup 1.0000x reference)
//
#include <hip/hip_runtime.h>

#define BM 64
#define BN 64
#define BK 32

// ---------------------------------------------------------------------------
// Weight transpose: Wt[k][o] = W[o][c*KHW + khw], k = khw*256 + c
// (makes conv GEMM B-side [K][N] with N contiguous)
// ---------------------------------------------------------------------------
__global__ __launch_bounds__(256) void transpose_w_kernel(
    const float* __restrict__ W, float* __restrict__ Wt, int KHW, int K)
{
    int k = blockIdx.x;          // 0..K-1
    int o = threadIdx.x;         // 0..255
    int khw = k >> 8;
    int c = k & 255;
    Wt[(size_t)k * 256 + o] = W[(size_t)o * K + (size_t)c * KHW + khw];
}

// ---------------------------------------------------------------------------
// Dense projection GEMM: C[b][m][n] = sum_k A[b][m][k] * Wm[n][k]  (+bias[n])
// K fixed = 256. Grid: (N/64, ceil(M/64), B)
// ---------------------------------------------------------------------------
__global__ __launch_bounds__(256) void gemm_proj_kernel(
    const float* __restrict__ A, long aStride, int M,
    const float* __restrict__ Wm, const float* __restrict__ bias,
    float* __restrict__ Cc, long cStride, int ldc)
{
    __shared__ float lds_a[BK][BM + 4];
    __shared__ float lds_b[BK][BN + 4];
    int t = threadIdx.x;
    int bz = blockIdx.z;
    int m0 = blockIdx.y * BM;
    int n0 = blockIdx.x * BN;
    int tx = t & 15, ty = t >> 4;
    int m_l = t >> 2, kc4 = (t & 3) * 4;
    int arow = m0 + m_l; if (arow >= M) arow = M - 1;
    const float* aptr = A + (size_t)bz * aStride + (size_t)arow * 256 + kc4;
    const float* wptr = Wm + (size_t)(n0 + m_l) * 256 + kc4;
    float acc[4][4] = {};
    for (int k0 = 0; k0 < 256; k0 += BK) {
        float4 av0 = *(const float4*)(aptr + k0);
        float4 av1 = *(const float4*)(aptr + k0 + 16);
        float4 bv0 = *(const float4*)(wptr + k0);
        float4 bv1 = *(const float4*)(wptr + k0 + 16);
        __syncthreads();
        lds_a[kc4 + 0][m_l] = av0.x;
        lds_a[kc4 + 1][m_l] = av0.y;
        lds_a[kc4 + 2][m_l] = av0.z;
        lds_a[kc4 + 3][m_l] = av0.w;
        lds_a[kc4 + 16][m_l] = av1.x;
        lds_a[kc4 + 17][m_l] = av1.y;
        lds_a[kc4 + 18][m_l] = av1.z;
        lds_a[kc4 + 19][m_l] = av1.w;
        lds_b[kc4 + 0][m_l] = bv0.x;
        lds_b[kc4 + 1][m_l] = bv0.y;
        lds_b[kc4 + 2][m_l] = bv0.z;
        lds_b[kc4 + 3][m_l] = bv0.w;
        lds_b[kc4 + 16][m_l] = bv1.x;
        lds_b[kc4 + 17][m_l] = bv1.y;
        lds_b[kc4 + 18][m_l] = bv1.z;
        lds_b[kc4 + 19][m_l] = bv1.w;
        __syncthreads();
        #pragma unroll
        for (int kk = 0; kk < BK; ++kk) {
            float4 a4 = *(const float4*)&lds_a[kk][ty * 4];
            float4 b4 = *(const float4*)&lds_b[kk][tx * 4];
            float ar[4] = {a4.x, a4.y, a4.z, a4.w};
            float br[4] = {b4.x, b4.y, b4.z, b4.w};
            #pragma unroll
            for (int i = 0; i < 4; ++i)
                #pragma unroll
                for (int jj = 0; jj < 4; ++jj)
                    acc[i][jj] += ar[i] * br[jj];
        }
    }
    float bj[4] = {0.f, 0.f, 0.f, 0.f};
    if (bias) {
        bj[0] = bias[n0 + tx * 4 + 0];
        bj[1] = bias[n0 + tx * 4 + 1];
        bj[2] = bias[n0 + tx * 4 + 2];
        bj[3] = bias[n0 + tx * 4 + 3];
    }
    #pragma unroll
    for (int i = 0; i < 4; ++i) {
        int mr = m0 + ty * 4 + i;
        if (mr < M) {
            float4 o4;
            o4.x = acc[i][0] + bj[0];
            o4.y = acc[i][1] + bj[1];
            o4.z = acc[i][2] + bj[2];
            o4.w = acc[i][3] + bj[3];
            *(float4*)(Cc + (size_t)bz * cStride + (size_t)mr * ldc + n0 + tx * 4) = o4;
        }
    }
}

// ---------------------------------------------------------------------------
// Conv (kernel==stride) as implicit GEMM with split-K + atomic accumulation.
// M = 392 (b*49 + patch), N = 256 (out ch), K = KHW*256, k = khw*256 + c.
// A[m][k] = x[b, (ph*s+kh)*Wimg + pw*s+kw, c];  B[k][n] = Wt[k][n].
// Grid: (4, 7, kslices). out must be pre-zeroed; bias applied later in LN.
// ---------------------------------------------------------------------------
__global__ __launch_bounds__(256) void conv_gemm_kernel(
    const float* __restrict__ x, int Nx, int Wimg, int lgs,
    const float* __restrict__ Wt, int kPerSlice,
    float* __restrict__ out)
{
    __shared__ float lds_a[BK][BM + 4];
    __shared__ float lds_b[BK][BN];
    int t = threadIdx.x;
    int m0 = blockIdx.y * BM;
    int n0 = blockIdx.x * BN;
    int kbase = blockIdx.z * kPerSlice;
    int s = 1 << lgs;
    int tx = t & 15, ty = t >> 4;
    int m_l = t >> 2, kc4 = (t & 3) * 4;
    int m_g = m0 + m_l; if (m_g > 391) m_g = 391;
    int bb = m_g / 49, p = m_g % 49;
    int ph = p / 7, pw = p % 7;
    const float* abase = x + ((size_t)bb * Nx + (size_t)(ph * s) * Wimg + pw * s) * 256 + kc4;
    int k_l = ty, noff = tx * 4;
    float acc[4][4] = {};
    for (int ko = 0; ko < kPerSlice; ko += BK) {
        int k0 = kbase + ko;
        int khw = k0 >> 8, c0 = k0 & 255;
        int kh = khw >> lgs, kw = khw & (s - 1);
        const float* ap = abase + (size_t)(kh * Wimg + kw) * 256 + c0;
        float4 av0 = *(const float4*)(ap);
        float4 av1 = *(const float4*)(ap + 16);
        const float* bp = Wt + (size_t)(k0 + k_l) * 256 + n0 + noff;
        float4 bv0 = *(const float4*)(bp);
        float4 bv1 = *(const float4*)(bp + 16 * 256);
        __syncthreads();
        lds_a[kc4 + 0][m_l] = av0.x;
        lds_a[kc4 + 1][m_l] = av0.y;
        lds_a[kc4 + 2][m_l] = av0.z;
        lds_a[kc4 + 3][m_l] = av0.w;
        lds_a[kc4 + 16][m_l] = av1.x;
        lds_a[kc4 + 17][m_l] = av1.y;
        lds_a[kc4 + 18][m_l] = av1.z;
        lds_a[kc4 + 19][m_l] = av1.w;
        *(float4*)&lds_b[k_l][noff] = bv0;
        *(float4*)&lds_b[k_l + 16][noff] = bv1;
        __syncthreads();
        #pragma unroll
        for (int kk = 0; kk < BK; ++kk) {
            float4 a4 = *(const float4*)&lds_a[kk][ty * 4];
            float4 b4 = *(const float4*)&lds_b[kk][tx * 4];
            float ar[4] = {a4.x, a4.y, a4.z, a4.w};
            float br[4] = {b4.x, b4.y, b4.z, b4.w};
            #pragma unroll
            for (int i = 0; i < 4; ++i)
                #pragma unroll
                for (int jj = 0; jj < 4; ++jj)
                    acc[i][jj] += ar[i] * br[jj];
        }
    }
    #pragma unroll
    for (int i = 0; i < 4; ++i) {
        int mr = m0 + ty * 4 + i;
        if (mr < 392) {
            int b2 = mr / 49, p2 = mr % 49;
            float* orow = out + ((size_t)b2 * 98 + p2) * 256 + n0 + tx * 4;
            #pragma unroll
            for (int jj = 0; jj < 4; ++jj)
                atomicAdd(&orow[jj], acc[i][jj]);
        }
    }
}

// ---------------------------------------------------------------------------
// LayerNorm over C=256 per row (8*98 rows); adds conv bias first.
// Branch 0 = rows with (row%98)<49, branch 1 otherwise.
// ---------------------------------------------------------------------------
__global__ __launch_bounds__(256) void ln_kernel(
    const float* __restrict__ xr,
    const float* __restrict__ srb0, const float* __restrict__ srb1,
    const float* __restrict__ n0w, const float* __restrict__ n0b,
    const float* __restrict__ n1w, const float* __restrict__ n1b,
    float* __restrict__ ln)
{
    int row = blockIdx.x;            // 0..783
    int j = row % 98;
    bool br1 = (j >= 49);
    int c = threadIdx.x;
    float v = xr[(size_t)row * 256 + c] + (br1 ? srb1[c] : srb0[c]);
    __shared__ float red[8];
    float sum = v;
    #pragma unroll
    for (int off = 32; off; off >>= 1) sum += __shfl_down(sum, off, 64);
    int wid = c >> 6, lane = c & 63;
    if (lane == 0) red[wid] = sum;
    __syncthreads();
    float mu = (red[0] + red[1] + red[2] + red[3]) * (1.0f / 256.0f);
    float dv = v - mu;
    float s2 = dv * dv;
    #pragma unroll
    for (int off = 32; off; off >>= 1) s2 += __shfl_down(s2, off, 64);
    if (lane == 0) red[4 + wid] = s2;
    __syncthreads();
    float var = (red[4] + red[5] + red[6] + red[7]) * (1.0f / 256.0f);
    float r = rsqrtf(var + 1e-5f);
    float w = br1 ? n1w[c] : n0w[c];
    float bb = br1 ? n1b[c] : n0b[c];
    ln[(size_t)row * 256 + c] = dv * r * w + bb;
}

// ---------------------------------------------------------------------------
// Attention: per (b,h), 98 keys in LDS, one query per thread, online softmax.
// Yq: [B][3920][256] (head h = cols h*32..); kv: [B][98][512] (K then V).
// Xc: [B][3920][256].
// ---------------------------------------------------------------------------
__global__ __launch_bounds__(256) void attn_kernel(
    const float* __restrict__ Yq, const float* __restrict__ kv,
    float* __restrict__ Xc)
{
    __shared__ float lk[98 * 32];
    __shared__ float lv[98 * 32];
    int bh = blockIdx.y;
    int b = bh >> 3, h = bh & 7;
    const float* kvb = kv + (size_t)b * 98 * 512;
    for (int idx = threadIdx.x; idx < 98 * 32; idx += 256) {
        int j = idx >> 5, d = idx & 31;
        lk[idx] = kvb[j * 512 + h * 32 + d];
        lv[idx] = kvb[j * 512 + 256 + h * 32 + d];
    }
    __syncthreads();
    int n = blockIdx.x * 256 + threadIdx.x;
    if (n >= 3920) return;
    const float* qp = Yq + ((size_t)b * 3920 + n) * 256 + h * 32;
    float q[32];
    #pragma unroll
    for (int d4 = 0; d4 < 8; ++d4) {
        float4 v = *(const float4*)(qp + d4 * 4);
        q[d4 * 4 + 0] = v.x; q[d4 * 4 + 1] = v.y;
        q[d4 * 4 + 2] = v.z; q[d4 * 4 + 3] = v.w;
    }
    float m = -1e30f, l = 0.0f;
    float acc[32];
    #pragma unroll
    for (int d = 0; d < 32; ++d) acc[d] = 0.0f;
    for (int j = 0; j < 98; ++j) {
        const float* kr = lk + j * 32;
        float sdot = 0.0f;
        #pragma unroll
        for (int d = 0; d < 32; ++d) sdot += q[d] * kr[d];
        sdot *= 0.1767766952966369f;   // 32^-0.5
        float nm = fmaxf(m, sdot);
        float so = __expf(m - nm);     // 1 when m==nm
        float pp = __expf(sdot - nm);
        l = l * so + pp;
        const float* vr = lv + j * 32;
        #pragma unroll
        for (int d = 0; d < 32; ++d) acc[d] = acc[d] * so + pp * vr[d];
        m = nm;
    }
    float inv = 1.0f / l;
    float* op = Xc + ((size_t)b * 3920 + n) * 256 + h * 32;
    #pragma unroll
    for (int d4 = 0; d4 < 8; ++d4) {
        float4 v;
        v.x = acc[d4 * 4 + 0] * inv; v.y = acc[d4 * 4 + 1] * inv;
        v.z = acc[d4 * 4 + 2] * inv; v.w = acc[d4 * 4 + 3] * inv;
        *(float4*)(op + d4 * 4) = v;
    }
}

// ---------------------------------------------------------------------------
extern "C" void kernel_launch(void* const* d_in, const int* in_sizes, int n_in,
                              void* d_out, int out_size, void* d_ws, size_t ws_size,
                              hipStream_t stream)
{
    const float* x0     = (const float*)d_in[0];
    const float* x1     = (const float*)d_in[1];
    const float* q_w    = (const float*)d_in[2];
    const float* kv_w   = (const float*)d_in[3];
    const float* proj_w = (const float*)d_in[4];
    const float* proj_b = (const float*)d_in[5];
    const float* sr0_w  = (const float*)d_in[6];
    const float* sr0_b  = (const float*)d_in[7];
    const float* sr1_w  = (const float*)d_in[8];
    const float* sr1_b  = (const float*)d_in[9];
    const float* n0w    = (const float*)d_in[10];
    const float* n0b    = (const float*)d_in[11];
    const float* n1w    = (const float*)d_in[12];
    const float* n1b    = (const float*)d_in[13];
    float* out = (float*)d_out;

    float* ws  = (float*)d_ws;
    float* Yq  = ws;                    // 8,028,160 fp32 : Q-proj [8][3920][256]
    float* Xc  = Yq + 8028160;          // 8,028,160 : attn out [8][3920][256]
    float* xr  = Xc + 8028160;          // 200,704  : conv out [8][98][256]
    float* lnb = xr + 200704;           // 200,704  : layernorm out
    float* kvb = lnb + 200704;          // 401,408  : kv proj [8][98][512]
    float* Wt0 = kvb + 401408;          // 4,194,304 : sr0_w transposed [16384][256]
    float* Wt1 = Wt0 + 4194304;         // 1,048,576 : sr1_w transposed [4096][256]
    (void)ws_size; (void)in_sizes; (void)n_in; (void)out_size;

    // conv output accumulator must be zero (split-K atomics)
    hipMemsetAsync(xr, 0, 200704 * sizeof(float), stream);

    // weight transposes
    transpose_w_kernel<<<16384, 256, 0, stream>>>(sr0_w, Wt0, 64, 16384);
    transpose_w_kernel<<<4096, 256, 0, stream>>>(sr1_w, Wt1, 16, 4096);

    // Q projection (both branches write into Yq)
    gemm_proj_kernel<<<dim3(4, 49, 8), 256, 0, stream>>>(
        x0, 3136L * 256, 3136, q_w, nullptr, Yq, 3920L * 256, 256);
    gemm_proj_kernel<<<dim3(4, 13, 8), 256, 0, stream>>>(
        x1, 784L * 256, 784, q_w, nullptr, Yq + 3136L * 256, 3920L * 256, 256);

    // spatial-reduction convs (split-K, atomic accumulate into xr)
    conv_gemm_kernel<<<dim3(4, 7, 16), 256, 0, stream>>>(
        x0, 3136, 56, 3, Wt0, 1024, xr);
    conv_gemm_kernel<<<dim3(4, 7, 8), 256, 0, stream>>>(
        x1, 784, 28, 2, Wt1, 512, xr + 49 * 256);

    // layernorm (+conv bias)
    ln_kernel<<<784, 256, 0, stream>>>(xr, sr0_b, sr1_b, n0w, n0b, n1w, n1b, lnb);

    // KV projection
    gemm_proj_kernel<<<dim3(8, 2, 8), 256, 0, stream>>>(
        lnb, 98L * 256, 98, kv_w, nullptr, kvb, 98L * 512, 512);

    // attention
    attn_kernel<<<dim3(16, 64), 256, 0, stream>>>(Yq, kvb, Xc);

    // output projection (+bias)
    gemm_proj_kernel<<<dim3(4, 62, 8), 256, 0, stream>>>(
        Xc, 3920L * 256, 3920, proj_w, proj_b, out, 3920L * 256, 256);
}

// Round 3
// 167.123 us; speedup vs baseline: 2.2213x; 2.2213x over previous
//
#include <hip/hip_runtime.h>

typedef unsigned short u16;
typedef unsigned int u32;
typedef float f4 __attribute__((ext_vector_type(4)));
typedef short s8v __attribute__((ext_vector_type(8)));
typedef unsigned short u16x4 __attribute__((ext_vector_type(4)));

__device__ __forceinline__ u16 f2bf(float f) {
    u32 u = __float_as_uint(f);
    u32 r = (u + 0x7FFFu + ((u >> 16) & 1u)) >> 16;
    return (u16)r;
}

#define GLDS16(g, l)                                                                   \
    __builtin_amdgcn_global_load_lds((const __attribute__((address_space(1))) u32*)(g),\
                                     (__attribute__((address_space(3))) u32*)(l), 16, 0, 0)

// ---------------------------------------------------------------------------
// flat fp32 -> bf16 convert (n4 = element_count/4)
// ---------------------------------------------------------------------------
__global__ __launch_bounds__(256) void cvt_kernel(
    const float* __restrict__ in, u16* __restrict__ out, int n4)
{
    int i = blockIdx.x * 256 + threadIdx.x;
    if (i < n4) {
        f4 v = *(const f4*)(in + (size_t)i * 4);
        u16x4 o;
        o[0] = f2bf(v[0]); o[1] = f2bf(v[1]); o[2] = f2bf(v[2]); o[3] = f2bf(v[3]);
        *(u16x4*)(out + (size_t)i * 4) = o;
    }
}

// ---------------------------------------------------------------------------
// conv weight: W[o][c][khw] (fp32) -> Wc[o][khw*256 + c] (bf16)
// ---------------------------------------------------------------------------
__global__ __launch_bounds__(256) void convw_kernel(
    const float* __restrict__ Ww, u16* __restrict__ Wc, int KHW)
{
    int o = blockIdx.x, c = threadIdx.x;
    const float* src = Ww + ((size_t)o * 256 + c) * KHW;
    for (int khw = 0; khw < KHW; ++khw)
        Wc[((size_t)o * KHW + khw) * 256 + c] = f2bf(src[khw]);
}

// ---------------------------------------------------------------------------
// bf16 MFMA GEMM: C[m][n] = sum_k A[m][k] * Bw[n][k]  (+bias)
// tile 128x128, BK=64, 4 waves (each 64x64 = 4x4 16x16x32 frags)
// A,B staged via global_load_lds, pre-swizzled source + swizzled ds_read
// ---------------------------------------------------------------------------
__global__ __launch_bounds__(256) void gemm_kernel(
    const u16* __restrict__ A, long aBatch, int M,
    const u16* __restrict__ Bw, int K,
    float* __restrict__ C, long cBatch, int ldc,
    const float* __restrict__ bias)
{
    __shared__ u16 lsA[128 * 64];
    __shared__ u16 lsB[128 * 64];
    int tid = threadIdx.x;
    int w = tid >> 6, l = tid & 63, g = l >> 4, lq = l & 15;
    int wr = w >> 1, wc = w & 1;
    int m0 = blockIdx.y * 128, n0 = blockIdx.x * 128;
    int bz = blockIdx.z;
    const u16* Ab = A + (size_t)bz * aBatch;

    long aoff[4], boff[4];
    #pragma unroll
    for (int i = 0; i < 4; ++i) {
        int p = (w * 4 + i) * 64 + l;
        int r = p >> 3, cp = p & 7;
        int ar = m0 + r; ar = ar < M ? ar : M - 1;
        aoff[i] = (long)ar * K + ((cp ^ (r & 7)) << 3);
        boff[i] = (long)(n0 + r) * K + ((cp ^ (r & 7)) << 3);
    }
    f4 acc[4][4];
    #pragma unroll
    for (int i = 0; i < 4; ++i)
        #pragma unroll
        for (int j = 0; j < 4; ++j) acc[i][j] = (f4){0.f, 0.f, 0.f, 0.f};

    for (int k0 = 0; k0 < K; k0 += 64) {
        __syncthreads();
        #pragma unroll
        for (int i = 0; i < 4; ++i)
            GLDS16(Ab + aoff[i] + k0, &lsA[(w * 4 + i) * 512]);
        #pragma unroll
        for (int i = 0; i < 4; ++i)
            GLDS16(Bw + boff[i] + k0, &lsB[(w * 4 + i) * 512]);
        __syncthreads();
        #pragma unroll
        for (int kk = 0; kk < 2; ++kk) {
            s8v af[4], bf[4];
            #pragma unroll
            for (int mf = 0; mf < 4; ++mf) {
                int row = wr * 64 + mf * 16 + lq;
                int ph = (kk * 4 + g) ^ (row & 7);
                af[mf] = *(const s8v*)&lsA[row * 64 + ph * 8];
            }
            #pragma unroll
            for (int nf = 0; nf < 4; ++nf) {
                int row = wc * 64 + nf * 16 + lq;
                int ph = (kk * 4 + g) ^ (row & 7);
                bf[nf] = *(const s8v*)&lsB[row * 64 + ph * 8];
            }
            #pragma unroll
            for (int mf = 0; mf < 4; ++mf)
                #pragma unroll
                for (int nf = 0; nf < 4; ++nf)
                    acc[mf][nf] = __builtin_amdgcn_mfma_f32_16x16x32_bf16(
                        af[mf], bf[nf], acc[mf][nf], 0, 0, 0);
        }
    }
    float* Cb = C + (size_t)bz * cBatch;
    #pragma unroll
    for (int mf = 0; mf < 4; ++mf) {
        #pragma unroll
        for (int r = 0; r < 4; ++r) {
            int grow = m0 + wr * 64 + mf * 16 + g * 4 + r;
            if (grow < M) {
                #pragma unroll
                for (int nf = 0; nf < 4; ++nf) {
                    int col = n0 + wc * 64 + nf * 16 + lq;
                    float v = acc[mf][nf][r];
                    if (bias) v += bias[col];
                    Cb[(size_t)grow * ldc + col] = v;
                }
            }
        }
    }
}

// ---------------------------------------------------------------------------
// conv (kernel==stride) as MFMA GEMM, split-K into slice buffers.
// M=392 (b*49+p), N=256, K = KHW*256, k = khw*256 + c. Grid (2, 4, nslices).
// Co[slice][392][256] fp32, summed later in LN. nslices*Ksl MUST equal Kc.
// ---------------------------------------------------------------------------
__global__ __launch_bounds__(256) void conv_kernel(
    const u16* __restrict__ Xb, int Npix, int Wimg, int lgs,
    const u16* __restrict__ Wc, int Kc, int Ksl,
    float* __restrict__ Co)
{
    __shared__ u16 lsA[128 * 64];
    __shared__ u16 lsB[128 * 64];
    int tid = threadIdx.x;
    int w = tid >> 6, l = tid & 63, g = l >> 4, lq = l & 15;
    int wr = w >> 1, wc = w & 1;
    int m0 = blockIdx.y * 128, n0 = blockIdx.x * 128;
    int z = blockIdx.z;
    int s = 1 << lgs;

    long aoff[4], boff[4];
    #pragma unroll
    for (int i = 0; i < 4; ++i) {
        int p = (w * 4 + i) * 64 + l;
        int r = p >> 3, cp = p & 7;
        int rr = m0 + r; rr = rr < 392 ? rr : 391;
        int bb = rr / 49, pp = rr % 49;
        int ph = pp / 7, pw = pp % 7;
        aoff[i] = ((long)bb * Npix + (long)(ph * Wimg + pw) * s) * 256 + ((cp ^ (r & 7)) << 3);
        boff[i] = (long)(n0 + r) * Kc + ((cp ^ (r & 7)) << 3);
    }
    f4 acc[4][4];
    #pragma unroll
    for (int i = 0; i < 4; ++i)
        #pragma unroll
        for (int j = 0; j < 4; ++j) acc[i][j] = (f4){0.f, 0.f, 0.f, 0.f};

    int kbase = z * Ksl;
    for (int ko = 0; ko < Ksl; ko += 64) {
        int k0 = kbase + ko;
        int khw = k0 >> 8;
        int kh = khw >> lgs, kw = khw & (s - 1);
        long adelta = (long)(kh * Wimg + kw) * 256 + (k0 & 255);
        __syncthreads();
        #pragma unroll
        for (int i = 0; i < 4; ++i)
            GLDS16(Xb + aoff[i] + adelta, &lsA[(w * 4 + i) * 512]);
        #pragma unroll
        for (int i = 0; i < 4; ++i)
            GLDS16(Wc + boff[i] + k0, &lsB[(w * 4 + i) * 512]);
        __syncthreads();
        #pragma unroll
        for (int kk = 0; kk < 2; ++kk) {
            s8v af[4], bf[4];
            #pragma unroll
            for (int mf = 0; mf < 4; ++mf) {
                int row = wr * 64 + mf * 16 + lq;
                int ph2 = (kk * 4 + g) ^ (row & 7);
                af[mf] = *(const s8v*)&lsA[row * 64 + ph2 * 8];
            }
            #pragma unroll
            for (int nf = 0; nf < 4; ++nf) {
                int row = wc * 64 + nf * 16 + lq;
                int ph2 = (kk * 4 + g) ^ (row & 7);
                bf[nf] = *(const s8v*)&lsB[row * 64 + ph2 * 8];
            }
            #pragma unroll
            for (int mf = 0; mf < 4; ++mf)
                #pragma unroll
                for (int nf = 0; nf < 4; ++nf)
                    acc[mf][nf] = __builtin_amdgcn_mfma_f32_16x16x32_bf16(
                        af[mf], bf[nf], acc[mf][nf], 0, 0, 0);
        }
    }
    float* Cb = Co + (size_t)z * 392 * 256;
    #pragma unroll
    for (int mf = 0; mf < 4; ++mf) {
        #pragma unroll
        for (int r = 0; r < 4; ++r) {
            int grow = m0 + wr * 64 + mf * 16 + g * 4 + r;
            if (grow < 392) {
                #pragma unroll
                for (int nf = 0; nf < 4; ++nf) {
                    int col = n0 + wc * 64 + nf * 16 + lq;
                    Cb[(size_t)grow * 256 + col] = acc[mf][nf][r];
                }
            }
        }
    }
}

// ---------------------------------------------------------------------------
// LayerNorm: sum conv slices + conv bias, normalize, write bf16.
// ---------------------------------------------------------------------------
__global__ __launch_bounds__(256) void ln_kernel(
    const float* __restrict__ xr0, const float* __restrict__ xr1,
    const float* __restrict__ srb0, const float* __restrict__ srb1,
    const float* __restrict__ n0w, const float* __restrict__ n0b,
    const float* __restrict__ n1w, const float* __restrict__ n1b,
    u16* __restrict__ lnb)
{
    int row = blockIdx.x;            // 0..783
    int b = row / 98, j = row % 98;
    int c = threadIdx.x;
    const float* src; int sidx, ns;
    const float *bs, *nw, *nb;
    if (j < 49) { src = xr0; sidx = b * 49 + j;       ns = 32; bs = srb0; nw = n0w; nb = n0b; }
    else        { src = xr1; sidx = b * 49 + (j - 49); ns = 8; bs = srb1; nw = n1w; nb = n1b; }
    float v = bs[c];
    for (int sl = 0; sl < ns; ++sl) v += src[(size_t)sl * 100352 + (size_t)sidx * 256 + c];
    __shared__ float red[8];
    float sumv = v;
    #pragma unroll
    for (int off = 32; off; off >>= 1) sumv += __shfl_down(sumv, off, 64);
    int wid = c >> 6, lane = c & 63;
    if (lane == 0) red[wid] = sumv;
    __syncthreads();
    float mu = (red[0] + red[1] + red[2] + red[3]) * (1.0f / 256.0f);
    float dv = v - mu;
    float s2 = dv * dv;
    #pragma unroll
    for (int off = 32; off; off >>= 1) s2 += __shfl_down(s2, off, 64);
    if (lane == 0) red[4 + wid] = s2;
    __syncthreads();
    float var = (red[4] + red[5] + red[6] + red[7]) * (1.0f / 256.0f);
    float rr = rsqrtf(var + 1e-5f);
    lnb[(size_t)row * 256 + c] = f2bf(dv * rr * nw[c] + nb[c]);
}

// ---------------------------------------------------------------------------
// MFMA attention. Block = (b,h) x 64 queries (4 waves x 16q).
// Swapped QK^T (mfma(K,Q) -> lane-major keys), wave-parallel softmax,
// P->LDS (bf16, /l folded in), PV = mfma(P^T, V) with V transposed in LDS.
// ---------------------------------------------------------------------------
#define SCALE_F 0.1767766952966369f
__global__ __launch_bounds__(256) void attn_kernel(
    const float* __restrict__ Yq, const float* __restrict__ kvb,
    u16* __restrict__ Xc)
{
    __shared__ u16 Qs[64 * 40];
    __shared__ u16 Ks[112 * 40];
    __shared__ u16 Vt[32 * 136];
    __shared__ u16 Ps[4][16 * 136];
    __shared__ float Ot[4][16 * 36];
    int tid = threadIdx.x;
    int w = tid >> 6, l = tid & 63, g = l >> 4, lq = l & 15;
    int bh = blockIdx.y, b = bh >> 3, h = bh & 7;
    int n0 = blockIdx.x * 64;

    {   // stage Q (64 rows x 32, clamped)
        int r = tid >> 2, c8 = (tid & 3) * 8;
        int qr = n0 + r; qr = qr < 3920 ? qr : 3919;
        const float* qp = Yq + ((size_t)b * 3920 + qr) * 256 + h * 32 + c8;
        f4 v0 = *(const f4*)qp, v1 = *(const f4*)(qp + 4);
        u16* d = &Qs[r * 40 + c8];
        d[0] = f2bf(v0[0]); d[1] = f2bf(v0[1]); d[2] = f2bf(v0[2]); d[3] = f2bf(v0[3]);
        d[4] = f2bf(v1[0]); d[5] = f2bf(v1[1]); d[6] = f2bf(v1[2]); d[7] = f2bf(v1[3]);
    }
    // stage K rows 0..111 (>=98 zeroed)
    for (int idx = tid; idx < 224; idx += 256) {
        int jr = idx >> 1, half = idx & 1;
        u16* d = &Ks[jr * 40 + half * 16];
        if (jr < 98) {
            const float* kp = kvb + ((size_t)b * 98 + jr) * 512 + h * 32 + half * 16;
            #pragma unroll
            for (int q4 = 0; q4 < 4; ++q4) {
                f4 v = *(const f4*)(kp + q4 * 4);
                d[q4 * 4 + 0] = f2bf(v[0]); d[q4 * 4 + 1] = f2bf(v[1]);
                d[q4 * 4 + 2] = f2bf(v[2]); d[q4 * 4 + 3] = f2bf(v[3]);
            }
        } else {
            #pragma unroll
            for (int q4 = 0; q4 < 16; ++q4) d[q4] = 0;
        }
    }
    // stage V transposed: Vt[d][j]
    for (int idx = tid; idx < 3136; idx += 256) {
        int jr = idx >> 5, dd = idx & 31;
        Vt[dd * 136 + jr] = f2bf(kvb[((size_t)b * 98 + jr) * 512 + 256 + h * 32 + dd]);
    }
    // zero Vt keys 98..127 (NaN hygiene for the P=0 region)
    for (int idx = tid; idx < 32 * 30; idx += 256) {
        int dd = idx / 30, jr = 98 + idx % 30;
        Vt[dd * 136 + jr] = 0;
    }
    __syncthreads();

    // QK^T (swapped): S^T[key][q], 7 key-frags
    s8v qf = *(const s8v*)&Qs[(w * 16 + lq) * 40 + g * 8];
    f4 sacc[7];
    #pragma unroll
    for (int f = 0; f < 7; ++f) {
        s8v kf = *(const s8v*)&Ks[(f * 16 + lq) * 40 + g * 8];
        f4 zz = (f4){0.f, 0.f, 0.f, 0.f};
        sacc[f] = __builtin_amdgcn_mfma_f32_16x16x32_bf16(kf, qf, zz, 0, 0, 0);
    }
    // softmax over keys (lane-local 28 values + xor16/xor32 column reduce)
    float pm = -1e30f;
    float sv[7][4];
    #pragma unroll
    for (int f = 0; f < 7; ++f)
        #pragma unroll
        for (int r = 0; r < 4; ++r) {
            int key = f * 16 + g * 4 + r;
            float v = sacc[f][r] * SCALE_F;
            if (key >= 98) v = -1e30f;
            sv[f][r] = v;
            pm = fmaxf(pm, v);
        }
    pm = fmaxf(pm, __shfl_xor(pm, 16));
    pm = fmaxf(pm, __shfl_xor(pm, 32));
    float sum = 0.f;
    float pv[7][4];
    #pragma unroll
    for (int f = 0; f < 7; ++f)
        #pragma unroll
        for (int r = 0; r < 4; ++r) {
            float e = __expf(sv[f][r] - pm);
            pv[f][r] = e;
            sum += e;
        }
    sum += __shfl_xor(sum, 16);
    sum += __shfl_xor(sum, 32);
    float inv = 1.0f / sum;

    // write P (bf16, already /l), pad keys 112..127 with zeros
    u16* Pw = Ps[w];
    if (l < 32) {
        s8v zz = (s8v){0, 0, 0, 0, 0, 0, 0, 0};
        *(s8v*)&Pw[(l >> 1) * 136 + 112 + (l & 1) * 8] = zz;
    }
    #pragma unroll
    for (int f = 0; f < 7; ++f)
        #pragma unroll
        for (int pr = 0; pr < 2; ++pr) {
            u32 pk = (u32)f2bf(pv[f][2 * pr] * inv) |
                     ((u32)f2bf(pv[f][2 * pr + 1] * inv) << 16);
            *(u32*)&Pw[lq * 136 + f * 16 + g * 4 + pr * 2] = pk;
        }

    // PV: out[q][d] = sum_key P^T[q][key] * V[key][d]
    f4 o0 = (f4){0.f, 0.f, 0.f, 0.f}, o1 = (f4){0.f, 0.f, 0.f, 0.f};
    #pragma unroll
    for (int s4 = 0; s4 < 4; ++s4) {
        s8v pa = *(const s8v*)&Pw[lq * 136 + s4 * 32 + g * 8];
        s8v vf0 = *(const s8v*)&Vt[(0 * 16 + lq) * 136 + s4 * 32 + g * 8];
        s8v vf1 = *(const s8v*)&Vt[(1 * 16 + lq) * 136 + s4 * 32 + g * 8];
        o0 = __builtin_amdgcn_mfma_f32_16x16x32_bf16(pa, vf0, o0, 0, 0, 0);
        o1 = __builtin_amdgcn_mfma_f32_16x16x32_bf16(pa, vf1, o1, 0, 0, 0);
    }
    // bounce through LDS for coalesced bf16 store
    #pragma unroll
    for (int r = 0; r < 4; ++r) {
        Ot[w][(g * 4 + r) * 36 + 0 * 16 + lq] = o0[r];
        Ot[w][(g * 4 + r) * 36 + 1 * 16 + lq] = o1[r];
    }
    int qloc = l >> 2, c4 = l & 3;
    int qg = n0 + w * 16 + qloc;
    if (qg < 3920) {
        #pragma unroll
        for (int half = 0; half < 2; ++half) {
            int cc = c4 + half * 4;
            u16x4 ov;
            #pragma unroll
            for (int i = 0; i < 4; ++i) ov[i] = f2bf(Ot[w][qloc * 36 + cc * 4 + i]);
            *(u16x4*)(Xc + ((size_t)b * 3920 + qg) * 256 + h * 32 + cc * 4) = ov;
        }
    }
}

// ---------------------------------------------------------------------------
extern "C" void kernel_launch(void* const* d_in, const int* in_sizes, int n_in,
                              void* d_out, int out_size, void* d_ws, size_t ws_size,
                              hipStream_t stream)
{
    const float* x0     = (const float*)d_in[0];
    const float* x1     = (const float*)d_in[1];
    const float* q_w    = (const float*)d_in[2];
    const float* kv_w   = (const float*)d_in[3];
    const float* proj_w = (const float*)d_in[4];
    const float* proj_b = (const float*)d_in[5];
    const float* sr0_w  = (const float*)d_in[6];
    const float* sr0_b  = (const float*)d_in[7];
    const float* sr1_w  = (const float*)d_in[8];
    const float* sr1_b  = (const float*)d_in[9];
    const float* n0w    = (const float*)d_in[10];
    const float* n0b    = (const float*)d_in[11];
    const float* n1w    = (const float*)d_in[12];
    const float* n1b    = (const float*)d_in[13];
    (void)in_sizes; (void)n_in; (void)out_size; (void)ws_size;

    float* ws = (float*)d_ws;
    float* Yq  = ws;                               // [8][3920][256] fp32
    u16*  XcU  = (u16*)(ws + 8028160);             // Xc bf16 [31360][256]; overlays x0b/x1b
    u16*  x0b  = XcU;                              // [25088][256] bf16 (dead before attn)
    u16*  x1b  = XcU + 6422528;                    // [6272][256] bf16
    float* xr0 = ws + 12042240;                    // [32][392][256] fp32 slices
    float* xr1 = ws + 15253504;                    // [8][392][256]
    float* kvb = ws + 16056320;                    // [784][512] fp32
    u16*  lnb  = (u16*)(ws + 16457728);            // [784][256] bf16
    u16*  qwb  = (u16*)(ws + 16558080);            // [256][256] bf16
    u16*  kvwb = (u16*)(ws + 16590848);            // [512][256] bf16
    u16*  pwb  = (u16*)(ws + 16656384);            // [256][256] bf16
    u16*  Wc0  = (u16*)(ws + 16689152);            // [256][16384] bf16
    u16*  Wc1  = (u16*)(ws + 18786304);            // [256][4096] bf16

    // converts
    cvt_kernel<<<6272, 256, 0, stream>>>(x0, x0b, 1605632);
    cvt_kernel<<<1568, 256, 0, stream>>>(x1, x1b, 401408);
    cvt_kernel<<<64, 256, 0, stream>>>(q_w, qwb, 16384);
    cvt_kernel<<<128, 256, 0, stream>>>(kv_w, kvwb, 32768);
    cvt_kernel<<<64, 256, 0, stream>>>(proj_w, pwb, 16384);
    convw_kernel<<<256, 256, 0, stream>>>(sr0_w, Wc0, 64);
    convw_kernel<<<256, 256, 0, stream>>>(sr1_w, Wc1, 16);

    // Q projection (fp32 out)
    gemm_kernel<<<dim3(2, 25, 8), 256, 0, stream>>>(
        x0b, 3136L * 256, 3136, qwb, 256, Yq, 3920L * 256, 256, nullptr);
    gemm_kernel<<<dim3(2, 7, 8), 256, 0, stream>>>(
        x1b, 784L * 256, 784, qwb, 256, Yq + 3136L * 256, 3920L * 256, 256, nullptr);

    // spatial-reduction convs (split-K slice buffers)
    // branch0: 32 slices x 512 = 16384 = Kc; branch1: 8 slices x 512 = 4096 = Kc
    conv_kernel<<<dim3(2, 4, 32), 256, 0, stream>>>(x0b, 3136, 56, 3, Wc0, 16384, 512, xr0);
    conv_kernel<<<dim3(2, 4, 8), 256, 0, stream>>>(x1b, 784, 28, 2, Wc1, 4096, 512, xr1);

    // layernorm (+conv bias, slice reduce) -> bf16
    ln_kernel<<<784, 256, 0, stream>>>(xr0, xr1, sr0_b, sr1_b, n0w, n0b, n1w, n1b, lnb);

    // KV projection (fp32 out)
    gemm_kernel<<<dim3(4, 1, 8), 256, 0, stream>>>(
        lnb, 98L * 256, 98, kvwb, 256, kvb, 98L * 512, 512, nullptr);

    // attention -> Xc bf16
    attn_kernel<<<dim3(62, 64), 256, 0, stream>>>(Yq, kvb, XcU);

    // output projection (+bias) -> d_out fp32
    gemm_kernel<<<dim3(2, 245, 1), 256, 0, stream>>>(
        XcU, 0, 31360, pwb, 256, (float*)d_out, 0, 256, proj_b);
}

// Round 4
// 150.063 us; speedup vs baseline: 2.4739x; 1.1137x over previous
//
#include <hip/hip_runtime.h>

typedef unsigned short u16;
typedef unsigned int u32;
typedef float f4 __attribute__((ext_vector_type(4)));
typedef short s8v __attribute__((ext_vector_type(8)));
typedef unsigned short u16x4 __attribute__((ext_vector_type(4)));

__device__ __forceinline__ u16 f2bf(float f) {
    u32 u = __float_as_uint(f);
    u32 r = (u + 0x7FFFu + ((u >> 16) & 1u)) >> 16;
    return (u16)r;
}

#define GLDS16(g, l)                                                                   \
    __builtin_amdgcn_global_load_lds((const __attribute__((address_space(1))) u32*)(g),\
                                     (__attribute__((address_space(3))) u32*)(l), 16, 0, 0)

// ---------------------------------------------------------------------------
// flat fp32 -> bf16 convert (n4 = element_count/4)
// ---------------------------------------------------------------------------
__global__ __launch_bounds__(256) void cvt_kernel(
    const float* __restrict__ in, u16* __restrict__ out, int n4)
{
    int i = blockIdx.x * 256 + threadIdx.x;
    if (i < n4) {
        f4 v = *(const f4*)(in + (size_t)i * 4);
        u16x4 o;
        o[0] = f2bf(v[0]); o[1] = f2bf(v[1]); o[2] = f2bf(v[2]); o[3] = f2bf(v[3]);
        *(u16x4*)(out + (size_t)i * 4) = o;
    }
}

// ---------------------------------------------------------------------------
// conv weight: W[o][c][khw] (fp32) -> Wc[o][khw*256 + c] (bf16)
// ---------------------------------------------------------------------------
__global__ __launch_bounds__(256) void convw_kernel(
    const float* __restrict__ Ww, u16* __restrict__ Wc, int KHW)
{
    int o = blockIdx.x, c = threadIdx.x;
    const float* src = Ww + ((size_t)o * 256 + c) * KHW;
    for (int khw = 0; khw < KHW; ++khw)
        Wc[((size_t)o * KHW + khw) * 256 + c] = f2bf(src[khw]);
}

// ---------------------------------------------------------------------------
// bf16 MFMA GEMM: C[m][n] = sum_k A[m][k] * Bw[n][k]  (+bias)
// MODE 0: fp32 C out. MODE 1: bf16 C out. MODE 2: kv scatter epilogue
// (col<256 -> Kb[bh][j][d]; col>=256 -> Vtb[bh][d][j], bf16).
// ---------------------------------------------------------------------------
template<int MODE>
__global__ __launch_bounds__(256) void gemm_kernel(
    const u16* __restrict__ A, long aBatch, int M,
    const u16* __restrict__ Bw, int K,
    void* __restrict__ Cv, long cBatch, int ldc,
    const float* __restrict__ bias,
    u16* __restrict__ Kb, u16* __restrict__ Vtb)
{
    __shared__ u16 lsA[128 * 64];
    __shared__ u16 lsB[128 * 64];
    int tid = threadIdx.x;
    int w = tid >> 6, l = tid & 63, g = l >> 4, lq = l & 15;
    int wr = w >> 1, wc = w & 1;
    int m0 = blockIdx.y * 128, n0 = blockIdx.x * 128;
    int bz = blockIdx.z;
    const u16* Ab = A + (size_t)bz * aBatch;

    long aoff[4], boff[4];
    #pragma unroll
    for (int i = 0; i < 4; ++i) {
        int p = (w * 4 + i) * 64 + l;
        int r = p >> 3, cp = p & 7;
        int ar = m0 + r; ar = ar < M ? ar : M - 1;
        aoff[i] = (long)ar * K + ((cp ^ (r & 7)) << 3);
        boff[i] = (long)(n0 + r) * K + ((cp ^ (r & 7)) << 3);
    }
    f4 acc[4][4];
    #pragma unroll
    for (int i = 0; i < 4; ++i)
        #pragma unroll
        for (int j = 0; j < 4; ++j) acc[i][j] = (f4){0.f, 0.f, 0.f, 0.f};

    for (int k0 = 0; k0 < K; k0 += 64) {
        __syncthreads();
        #pragma unroll
        for (int i = 0; i < 4; ++i)
            GLDS16(Ab + aoff[i] + k0, &lsA[(w * 4 + i) * 512]);
        #pragma unroll
        for (int i = 0; i < 4; ++i)
            GLDS16(Bw + boff[i] + k0, &lsB[(w * 4 + i) * 512]);
        __syncthreads();
        #pragma unroll
        for (int kk = 0; kk < 2; ++kk) {
            s8v af[4], bf[4];
            #pragma unroll
            for (int mf = 0; mf < 4; ++mf) {
                int row = wr * 64 + mf * 16 + lq;
                int ph = (kk * 4 + g) ^ (row & 7);
                af[mf] = *(const s8v*)&lsA[row * 64 + ph * 8];
            }
            #pragma unroll
            for (int nf = 0; nf < 4; ++nf) {
                int row = wc * 64 + nf * 16 + lq;
                int ph = (kk * 4 + g) ^ (row & 7);
                bf[nf] = *(const s8v*)&lsB[row * 64 + ph * 8];
            }
            #pragma unroll
            for (int mf = 0; mf < 4; ++mf)
                #pragma unroll
                for (int nf = 0; nf < 4; ++nf)
                    acc[mf][nf] = __builtin_amdgcn_mfma_f32_16x16x32_bf16(
                        af[mf], bf[nf], acc[mf][nf], 0, 0, 0);
        }
    }
    #pragma unroll
    for (int mf = 0; mf < 4; ++mf) {
        #pragma unroll
        for (int r = 0; r < 4; ++r) {
            int grow = m0 + wr * 64 + mf * 16 + g * 4 + r;
            if (grow < M) {
                #pragma unroll
                for (int nf = 0; nf < 4; ++nf) {
                    int col = n0 + wc * 64 + nf * 16 + lq;
                    float v = acc[mf][nf][r];
                    if (MODE == 0) {
                        if (bias) v += bias[col];
                        ((float*)Cv)[(size_t)bz * cBatch + (size_t)grow * ldc + col] = v;
                    } else if (MODE == 1) {
                        ((u16*)Cv)[(size_t)bz * cBatch + (size_t)grow * ldc + col] = f2bf(v);
                    } else {
                        if (col < 256) {
                            int hh = col >> 5, d = col & 31;
                            Kb[((size_t)(bz * 8 + hh) * 112 + grow) * 32 + d] = f2bf(v);
                        } else {
                            int cc = col - 256;
                            int hh = cc >> 5, d = cc & 31;
                            Vtb[((size_t)(bz * 8 + hh) * 32 + d) * 112 + grow] = f2bf(v);
                        }
                    }
                }
            }
        }
    }
}

// ---------------------------------------------------------------------------
// conv (kernel==stride) as MFMA GEMM, split-K into slice buffers.
// M=392 (b*49+p), N=256, K = KHW*256. nslices*Ksl MUST equal Kc.
// ---------------------------------------------------------------------------
__global__ __launch_bounds__(256) void conv_kernel(
    const u16* __restrict__ Xb, int Npix, int Wimg, int lgs,
    const u16* __restrict__ Wc, int Kc, int Ksl,
    float* __restrict__ Co)
{
    __shared__ u16 lsA[128 * 64];
    __shared__ u16 lsB[128 * 64];
    int tid = threadIdx.x;
    int w = tid >> 6, l = tid & 63, g = l >> 4, lq = l & 15;
    int wr = w >> 1, wc = w & 1;
    int m0 = blockIdx.y * 128, n0 = blockIdx.x * 128;
    int z = blockIdx.z;
    int s = 1 << lgs;

    long aoff[4], boff[4];
    #pragma unroll
    for (int i = 0; i < 4; ++i) {
        int p = (w * 4 + i) * 64 + l;
        int r = p >> 3, cp = p & 7;
        int rr = m0 + r; rr = rr < 392 ? rr : 391;
        int bb = rr / 49, pp = rr % 49;
        int ph = pp / 7, pw = pp % 7;
        aoff[i] = ((long)bb * Npix + (long)(ph * Wimg + pw) * s) * 256 + ((cp ^ (r & 7)) << 3);
        boff[i] = (long)(n0 + r) * Kc + ((cp ^ (r & 7)) << 3);
    }
    f4 acc[4][4];
    #pragma unroll
    for (int i = 0; i < 4; ++i)
        #pragma unroll
        for (int j = 0; j < 4; ++j) acc[i][j] = (f4){0.f, 0.f, 0.f, 0.f};

    int kbase = z * Ksl;
    for (int ko = 0; ko < Ksl; ko += 64) {
        int k0 = kbase + ko;
        int khw = k0 >> 8;
        int kh = khw >> lgs, kw = khw & (s - 1);
        long adelta = (long)(kh * Wimg + kw) * 256 + (k0 & 255);
        __syncthreads();
        #pragma unroll
        for (int i = 0; i < 4; ++i)
            GLDS16(Xb + aoff[i] + adelta, &lsA[(w * 4 + i) * 512]);
        #pragma unroll
        for (int i = 0; i < 4; ++i)
            GLDS16(Wc + boff[i] + k0, &lsB[(w * 4 + i) * 512]);
        __syncthreads();
        #pragma unroll
        for (int kk = 0; kk < 2; ++kk) {
            s8v af[4], bf[4];
            #pragma unroll
            for (int mf = 0; mf < 4; ++mf) {
                int row = wr * 64 + mf * 16 + lq;
                int ph2 = (kk * 4 + g) ^ (row & 7);
                af[mf] = *(const s8v*)&lsA[row * 64 + ph2 * 8];
            }
            #pragma unroll
            for (int nf = 0; nf < 4; ++nf) {
                int row = wc * 64 + nf * 16 + lq;
                int ph2 = (kk * 4 + g) ^ (row & 7);
                bf[nf] = *(const s8v*)&lsB[row * 64 + ph2 * 8];
            }
            #pragma unroll
            for (int mf = 0; mf < 4; ++mf)
                #pragma unroll
                for (int nf = 0; nf < 4; ++nf)
                    acc[mf][nf] = __builtin_amdgcn_mfma_f32_16x16x32_bf16(
                        af[mf], bf[nf], acc[mf][nf], 0, 0, 0);
        }
    }
    float* Cb = Co + (size_t)z * 392 * 256;
    #pragma unroll
    for (int mf = 0; mf < 4; ++mf) {
        #pragma unroll
        for (int r = 0; r < 4; ++r) {
            int grow = m0 + wr * 64 + mf * 16 + g * 4 + r;
            if (grow < 392) {
                #pragma unroll
                for (int nf = 0; nf < 4; ++nf) {
                    int col = n0 + wc * 64 + nf * 16 + lq;
                    Cb[(size_t)grow * 256 + col] = acc[mf][nf][r];
                }
            }
        }
    }
}

// ---------------------------------------------------------------------------
// LayerNorm: sum conv slices + conv bias, normalize, write bf16.
// ---------------------------------------------------------------------------
__global__ __launch_bounds__(256) void ln_kernel(
    const float* __restrict__ xr0, const float* __restrict__ xr1,
    const float* __restrict__ srb0, const float* __restrict__ srb1,
    const float* __restrict__ n0w, const float* __restrict__ n0b,
    const float* __restrict__ n1w, const float* __restrict__ n1b,
    u16* __restrict__ lnb)
{
    int row = blockIdx.x;            // 0..783
    int b = row / 98, j = row % 98;
    int c = threadIdx.x;
    const float* src; int sidx, ns;
    const float *bs, *nw, *nb;
    if (j < 49) { src = xr0; sidx = b * 49 + j;       ns = 32; bs = srb0; nw = n0w; nb = n0b; }
    else        { src = xr1; sidx = b * 49 + (j - 49); ns = 8; bs = srb1; nw = n1w; nb = n1b; }
    float v = bs[c];
    for (int sl = 0; sl < ns; ++sl) v += src[(size_t)sl * 100352 + (size_t)sidx * 256 + c];
    __shared__ float red[8];
    float sumv = v;
    #pragma unroll
    for (int off = 32; off; off >>= 1) sumv += __shfl_down(sumv, off, 64);
    int wid = c >> 6, lane = c & 63;
    if (lane == 0) red[wid] = sumv;
    __syncthreads();
    float mu = (red[0] + red[1] + red[2] + red[3]) * (1.0f / 256.0f);
    float dv = v - mu;
    float s2 = dv * dv;
    #pragma unroll
    for (int off = 32; off; off >>= 1) s2 += __shfl_down(s2, off, 64);
    if (lane == 0) red[4 + wid] = s2;
    __syncthreads();
    float var = (red[4] + red[5] + red[6] + red[7]) * (1.0f / 256.0f);
    float rr = rsqrtf(var + 1e-5f);
    lnb[(size_t)row * 256 + c] = f2bf(dv * rr * nw[c] + nb[c]);
}

// ---------------------------------------------------------------------------
// MFMA attention v2 — all-bf16 I/O, XOR-swizzled LDS (GEMM-proven pattern).
// Block = (b,h) x 64 queries (4 waves x 16q). Kb[bh][112][32], Vtb[bh][32][112]
// pre-laid-out by kv-proj epilogue (rows/cols >=98 zeroed by memset).
// ---------------------------------------------------------------------------
#define SCALE_F 0.1767766952966369f
__global__ __launch_bounds__(256) void attn_kernel(
    const u16* __restrict__ Yq, const u16* __restrict__ Kb,
    const u16* __restrict__ Vtb, u16* __restrict__ Xc)
{
    __shared__ u16 Qs[64 * 32];
    __shared__ u16 Ks[112 * 32];
    __shared__ u16 VtS[64 * 64];       // R = d + 32*(key>=64), col = key%64
    __shared__ u16 Ps[4][16 * 128];
    __shared__ float Ot[4][16 * 36];
    int tid = threadIdx.x;
    int w = tid >> 6, l = tid & 63, g = l >> 4, lq = l & 15;
    int bh = blockIdx.y, b = bh >> 3, h = bh & 7;
    int n0 = blockIdx.x * 64;

    {   // Q: 64 rows x 32 bf16, one 16B chunk per thread, swizzled
        int r = tid >> 2, c = tid & 3;
        int qr = n0 + r; qr = qr < 3920 ? qr : 3919;
        s8v qv = *(const s8v*)(Yq + ((size_t)b * 3920 + qr) * 256 + h * 32 + c * 8);
        *(s8v*)&Qs[r * 32 + ((c ^ (r & 3)) * 8)] = qv;
    }
    // K: 112 rows x 32 bf16 (rows >=98 are zero in Kb)
    #pragma unroll
    for (int i = 0; i < 2; ++i) {
        int u = tid + i * 256;
        int row = u >> 2, c = u & 3;
        if (row < 112) {
            s8v kv = *(const s8v*)(Kb + ((size_t)bh * 112 + row) * 32 + c * 8);
            *(s8v*)&Ks[row * 32 + ((c ^ (row & 3)) * 8)] = kv;
        }
    }
    // V^T: VtS[64][64]; source Vtb[bh][d][112] (cols >=98 zero)
    #pragma unroll
    for (int i = 0; i < 2; ++i) {
        int u = tid + i * 256;
        int R = u >> 3, c3 = u & 7;
        int d = R & 31, j = (R >> 5) * 64 + c3 * 8;
        s8v vv;
        if (j < 112) vv = *(const s8v*)(Vtb + ((size_t)bh * 32 + d) * 112 + j);
        else         vv = (s8v){0, 0, 0, 0, 0, 0, 0, 0};
        *(s8v*)&VtS[R * 64 + ((c3 ^ (R & 7)) * 8)] = vv;
    }
    __syncthreads();

    // QK^T (swapped): S^T[key][q]
    int qrow = w * 16 + lq;
    s8v qf = *(const s8v*)&Qs[qrow * 32 + ((g ^ (lq & 3)) * 8)];
    f4 sacc[7];
    #pragma unroll
    for (int f = 0; f < 7; ++f) {
        int krow = f * 16 + lq;
        s8v kf = *(const s8v*)&Ks[krow * 32 + ((g ^ (lq & 3)) * 8)];
        f4 zz = (f4){0.f, 0.f, 0.f, 0.f};
        sacc[f] = __builtin_amdgcn_mfma_f32_16x16x32_bf16(kf, qf, zz, 0, 0, 0);
    }
    // softmax over keys
    float pm = -1e30f;
    float sv[7][4];
    #pragma unroll
    for (int f = 0; f < 7; ++f)
        #pragma unroll
        for (int r = 0; r < 4; ++r) {
            int key = f * 16 + g * 4 + r;
            float v = sacc[f][r] * SCALE_F;
            if (key >= 98) v = -1e30f;
            sv[f][r] = v;
            pm = fmaxf(pm, v);
        }
    pm = fmaxf(pm, __shfl_xor(pm, 16));
    pm = fmaxf(pm, __shfl_xor(pm, 32));
    float sum = 0.f;
    float pv[7][4];
    #pragma unroll
    for (int f = 0; f < 7; ++f)
        #pragma unroll
        for (int r = 0; r < 4; ++r) {
            float e = __expf(sv[f][r] - pm);
            pv[f][r] = e;
            sum += e;
        }
    sum += __shfl_xor(sum, 16);
    sum += __shfl_xor(sum, 32);
    float inv = 1.0f / sum;

    // P -> LDS, swizzled; zero keys 112..127
    u16* Pw = Ps[w];
    if (l < 32) {
        int row = l >> 1;
        int gr = (14 + (l & 1)) ^ (row & 7);
        *(s8v*)&Pw[row * 128 + gr * 8] = (s8v){0, 0, 0, 0, 0, 0, 0, 0};
    }
    #pragma unroll
    for (int f = 0; f < 7; ++f)
        #pragma unroll
        for (int pr = 0; pr < 2; ++pr) {
            u32 pk = (u32)f2bf(pv[f][2 * pr] * inv) |
                     ((u32)f2bf(pv[f][2 * pr + 1] * inv) << 16);
            int k = f * 16 + g * 4 + pr * 2;
            int gr = (k >> 3) ^ (lq & 7);
            *(u32*)&Pw[lq * 128 + gr * 8 + (k & 7)] = pk;
        }

    // PV: out[q][d] = sum_key P[q][key] * V^T[d][key]
    f4 o0 = (f4){0.f, 0.f, 0.f, 0.f}, o1 = (f4){0.f, 0.f, 0.f, 0.f};
    #pragma unroll
    for (int s4 = 0; s4 < 4; ++s4) {
        int gv = s4 * 4 + g;
        s8v pa = *(const s8v*)&Pw[lq * 128 + ((gv ^ (lq & 7)) * 8)];
        int gvv = (s4 & 1) * 4 + g;
        int Rb = 32 * (s4 >> 1);
        s8v vf0 = *(const s8v*)&VtS[(Rb + lq) * 64 + ((gvv ^ (lq & 7)) * 8)];
        s8v vf1 = *(const s8v*)&VtS[(Rb + 16 + lq) * 64 + ((gvv ^ (lq & 7)) * 8)];
        o0 = __builtin_amdgcn_mfma_f32_16x16x32_bf16(pa, vf0, o0, 0, 0, 0);
        o1 = __builtin_amdgcn_mfma_f32_16x16x32_bf16(pa, vf1, o1, 0, 0, 0);
    }
    // bounce through LDS for coalesced bf16 store
    #pragma unroll
    for (int r = 0; r < 4; ++r) {
        Ot[w][(g * 4 + r) * 36 + 0 * 16 + lq] = o0[r];
        Ot[w][(g * 4 + r) * 36 + 1 * 16 + lq] = o1[r];
    }
    int qloc = l >> 2, c4 = l & 3;
    int qg = n0 + w * 16 + qloc;
    if (qg < 3920) {
        #pragma unroll
        for (int half = 0; half < 2; ++half) {
            int cc = c4 + half * 4;
            u16x4 ov;
            #pragma unroll
            for (int i = 0; i < 4; ++i) ov[i] = f2bf(Ot[w][qloc * 36 + cc * 4 + i]);
            *(u16x4*)(Xc + ((size_t)b * 3920 + qg) * 256 + h * 32 + cc * 4) = ov;
        }
    }
}

// ---------------------------------------------------------------------------
extern "C" void kernel_launch(void* const* d_in, const int* in_sizes, int n_in,
                              void* d_out, int out_size, void* d_ws, size_t ws_size,
                              hipStream_t stream)
{
    const float* x0     = (const float*)d_in[0];
    const float* x1     = (const float*)d_in[1];
    const float* q_w    = (const float*)d_in[2];
    const float* kv_w   = (const float*)d_in[3];
    const float* proj_w = (const float*)d_in[4];
    const float* proj_b = (const float*)d_in[5];
    const float* sr0_w  = (const float*)d_in[6];
    const float* sr0_b  = (const float*)d_in[7];
    const float* sr1_w  = (const float*)d_in[8];
    const float* sr1_b  = (const float*)d_in[9];
    const float* n0w    = (const float*)d_in[10];
    const float* n0b    = (const float*)d_in[11];
    const float* n1w    = (const float*)d_in[12];
    const float* n1b    = (const float*)d_in[13];
    (void)in_sizes; (void)n_in; (void)out_size; (void)ws_size;

    float* ws = (float*)d_ws;
    u16*  Yq   = (u16*)ws;                         // [8][3920][256] bf16 (4,014,080 f32)
    u16*  XcU  = (u16*)(ws + 4014080);             // bf16 [31360][256]; overlays x0b/x1b
    u16*  x0b  = XcU;                              // [25088][256] bf16 (dead before attn)
    u16*  x1b  = XcU + 6422528;                    // [6272][256] bf16
    float* xr0 = ws + 8028160;                     // [32][392][256] fp32 slices
    float* xr1 = ws + 11239424;                    // [8][392][256]
    u16*  Kb   = (u16*)(ws + 12042240);            // [64][112][32] bf16
    u16*  Vtb  = (u16*)(ws + 12156928);            // [64][32][112] bf16
    u16*  lnb  = (u16*)(ws + 12271616);            // [784][256] bf16
    u16*  qwb  = (u16*)(ws + 12371968);            // [256][256] bf16
    u16*  kvwb = (u16*)(ws + 12404736);            // [512][256] bf16
    u16*  pwb  = (u16*)(ws + 12470272);            // [256][256] bf16
    u16*  Wc0  = (u16*)(ws + 12503040);            // [256][16384] bf16
    u16*  Wc1  = (u16*)(ws + 14600192);            // [256][4096] bf16

    // converts
    cvt_kernel<<<6272, 256, 0, stream>>>(x0, x0b, 1605632);
    cvt_kernel<<<1568, 256, 0, stream>>>(x1, x1b, 401408);
    cvt_kernel<<<64, 256, 0, stream>>>(q_w, qwb, 16384);
    cvt_kernel<<<128, 256, 0, stream>>>(kv_w, kvwb, 32768);
    cvt_kernel<<<64, 256, 0, stream>>>(proj_w, pwb, 16384);
    convw_kernel<<<256, 256, 0, stream>>>(sr0_w, Wc0, 64);
    convw_kernel<<<256, 256, 0, stream>>>(sr1_w, Wc1, 16);

    // zero K/V padded layouts (rows/cols >= 98 must be 0)
    hipMemsetAsync(Kb, 0, 2 * 229376 * sizeof(u16), stream);

    // Q projection -> bf16
    gemm_kernel<1><<<dim3(2, 25, 8), 256, 0, stream>>>(
        x0b, 3136L * 256, 3136, qwb, 256, Yq, 3920L * 256, 256, nullptr, nullptr, nullptr);
    gemm_kernel<1><<<dim3(2, 7, 8), 256, 0, stream>>>(
        x1b, 784L * 256, 784, qwb, 256, Yq + 3136L * 256, 3920L * 256, 256, nullptr, nullptr, nullptr);

    // spatial-reduction convs (split-K slice buffers)
    conv_kernel<<<dim3(2, 4, 32), 256, 0, stream>>>(x0b, 3136, 56, 3, Wc0, 16384, 512, xr0);
    conv_kernel<<<dim3(2, 4, 8), 256, 0, stream>>>(x1b, 784, 28, 2, Wc1, 4096, 512, xr1);

    // layernorm (+conv bias, slice reduce) -> bf16
    ln_kernel<<<784, 256, 0, stream>>>(xr0, xr1, sr0_b, sr1_b, n0w, n0b, n1w, n1b, lnb);

    // KV projection -> scatter to Kb / Vtb (bf16, attn-friendly layouts)
    gemm_kernel<2><<<dim3(4, 1, 8), 256, 0, stream>>>(
        lnb, 98L * 256, 98, kvwb, 256, nullptr, 0, 0, nullptr, Kb, Vtb);

    // attention -> Xc bf16
    attn_kernel<<<dim3(62, 64), 256, 0, stream>>>(Yq, Kb, Vtb, XcU);

    // output projection (+bias) -> d_out fp32
    gemm_kernel<0><<<dim3(2, 245, 1), 256, 0, stream>>>(
        XcU, 0, 31360, pwb, 256, (float*)d_out, 0, 256, proj_b, nullptr, nullptr);
}

// Round 5
// 129.735 us; speedup vs baseline: 2.8615x; 1.1567x over previous
//
#include <hip/hip_runtime.h>

typedef unsigned short u16;
typedef unsigned int u32;
typedef float f4 __attribute__((ext_vector_type(4)));
typedef short s8v __attribute__((ext_vector_type(8)));
typedef unsigned short u16x4 __attribute__((ext_vector_type(4)));

__device__ __forceinline__ u16 f2bf(float f) {
    u32 u = __float_as_uint(f);
    u32 r = (u + 0x7FFFu + ((u >> 16) & 1u)) >> 16;
    return (u16)r;
}

#define GLDS16(g, l)                                                                   \
    __builtin_amdgcn_global_load_lds((const __attribute__((address_space(1))) u32*)(g),\
                                     (__attribute__((address_space(3))) u32*)(l), 16, 0, 0)

// ---------------------------------------------------------------------------
// Fused prep: all fp32->bf16 converts + both conv-weight transposes.
// Unit = 4 output elements. Segment ranges (units):
//   [0,1605632)        x0 cvt
//   [1605632,2007040)  x1 cvt
//   [2007040,2023424)  q_w cvt
//   [2023424,2056192)  kv_w cvt
//   [2056192,2072576)  proj_w cvt
//   [2072576,3121152)  Wc0: Wc0[o][khw*256+c] = w0[o][c][khw], KHW=64
//   [3121152,3383296)  Wc1: KHW=16
// ---------------------------------------------------------------------------
__global__ __launch_bounds__(256) void prep_kernel(
    const float* __restrict__ x0, const float* __restrict__ x1,
    const float* __restrict__ qw, const float* __restrict__ kvw,
    const float* __restrict__ pw, const float* __restrict__ w0,
    const float* __restrict__ w1,
    u16* __restrict__ x0b, u16* __restrict__ x1b, u16* __restrict__ qwb,
    u16* __restrict__ kvwb, u16* __restrict__ pwb,
    u16* __restrict__ Wc0, u16* __restrict__ Wc1)
{
    for (int u = blockIdx.x * 256 + threadIdx.x; u < 3383296; u += gridDim.x * 256) {
        if (u < 2072576) {
            const float* src; u16* dst; int idx;
            if (u < 1605632)      { src = x0;  dst = x0b;  idx = u; }
            else if (u < 2007040) { src = x1;  dst = x1b;  idx = u - 1605632; }
            else if (u < 2023424) { src = qw;  dst = qwb;  idx = u - 2007040; }
            else if (u < 2056192) { src = kvw; dst = kvwb; idx = u - 2023424; }
            else                  { src = pw;  dst = pwb;  idx = u - 2056192; }
            f4 v = *(const f4*)(src + (size_t)idx * 4);
            u16x4 o;
            o[0] = f2bf(v[0]); o[1] = f2bf(v[1]); o[2] = f2bf(v[2]); o[3] = f2bf(v[3]);
            *(u16x4*)(dst + (size_t)idx * 4) = o;
        } else if (u < 3121152) {
            int e = (u - 2072576) * 4;
            int o = e >> 14, rem = e & 16383;
            int khw = rem >> 8, c = rem & 255;
            u16x4 ov;
            #pragma unroll
            for (int j = 0; j < 4; ++j)
                ov[j] = f2bf(w0[(size_t)o * 16384 + (size_t)(c + j) * 64 + khw]);
            *(u16x4*)(Wc0 + (size_t)e) = ov;
        } else {
            int e = (u - 3121152) * 4;
            int o = e >> 12, rem = e & 4095;
            int khw = rem >> 8, c = rem & 255;
            u16x4 ov;
            #pragma unroll
            for (int j = 0; j < 4; ++j)
                ov[j] = f2bf(w1[(size_t)o * 4096 + (size_t)(c + j) * 16 + khw]);
            *(u16x4*)(Wc1 + (size_t)e) = ov;
        }
    }
}

// ---------------------------------------------------------------------------
// bf16 MFMA GEMM: C[m][n] = sum_k A[m][k] * Bw[n][k]  (+bias)
// MODE 0: fp32 C out. MODE 2: kv scatter epilogue (col<256 -> Kb[bh][j][d];
// col>=256 -> Vtb[bh][d][j], bf16; rows/cols 98..111 zero-filled).
// ---------------------------------------------------------------------------
template<int MODE>
__global__ __launch_bounds__(256) void gemm_kernel(
    const u16* __restrict__ A, long aBatch, int M,
    const u16* __restrict__ Bw, int K,
    void* __restrict__ Cv, long cBatch, int ldc,
    const float* __restrict__ bias,
    u16* __restrict__ Kb, u16* __restrict__ Vtb)
{
    __shared__ u16 lsA[128 * 64];
    __shared__ u16 lsB[128 * 64];
    int tid = threadIdx.x;
    int w = tid >> 6, l = tid & 63, g = l >> 4, lq = l & 15;
    int wr = w >> 1, wc = w & 1;
    int m0 = blockIdx.y * 128, n0 = blockIdx.x * 128;
    int bz = blockIdx.z;
    const u16* Ab = A + (size_t)bz * aBatch;

    long aoff[4], boff[4];
    #pragma unroll
    for (int i = 0; i < 4; ++i) {
        int p = (w * 4 + i) * 64 + l;
        int r = p >> 3, cp = p & 7;
        int ar = m0 + r; ar = ar < M ? ar : M - 1;
        aoff[i] = (long)ar * K + ((cp ^ (r & 7)) << 3);
        boff[i] = (long)(n0 + r) * K + ((cp ^ (r & 7)) << 3);
    }
    f4 acc[4][4];
    #pragma unroll
    for (int i = 0; i < 4; ++i)
        #pragma unroll
        for (int j = 0; j < 4; ++j) acc[i][j] = (f4){0.f, 0.f, 0.f, 0.f};

    for (int k0 = 0; k0 < K; k0 += 64) {
        __syncthreads();
        #pragma unroll
        for (int i = 0; i < 4; ++i)
            GLDS16(Ab + aoff[i] + k0, &lsA[(w * 4 + i) * 512]);
        #pragma unroll
        for (int i = 0; i < 4; ++i)
            GLDS16(Bw + boff[i] + k0, &lsB[(w * 4 + i) * 512]);
        __syncthreads();
        #pragma unroll
        for (int kk = 0; kk < 2; ++kk) {
            s8v af[4], bf[4];
            #pragma unroll
            for (int mf = 0; mf < 4; ++mf) {
                int row = wr * 64 + mf * 16 + lq;
                int ph = (kk * 4 + g) ^ (row & 7);
                af[mf] = *(const s8v*)&lsA[row * 64 + ph * 8];
            }
            #pragma unroll
            for (int nf = 0; nf < 4; ++nf) {
                int row = wc * 64 + nf * 16 + lq;
                int ph = (kk * 4 + g) ^ (row & 7);
                bf[nf] = *(const s8v*)&lsB[row * 64 + ph * 8];
            }
            #pragma unroll
            for (int mf = 0; mf < 4; ++mf)
                #pragma unroll
                for (int nf = 0; nf < 4; ++nf)
                    acc[mf][nf] = __builtin_amdgcn_mfma_f32_16x16x32_bf16(
                        af[mf], bf[nf], acc[mf][nf], 0, 0, 0);
        }
    }
    #pragma unroll
    for (int mf = 0; mf < 4; ++mf) {
        #pragma unroll
        for (int r = 0; r < 4; ++r) {
            int grow = m0 + wr * 64 + mf * 16 + g * 4 + r;
            bool ok = (MODE == 2) ? (grow < 112) : (grow < M);
            if (ok) {
                #pragma unroll
                for (int nf = 0; nf < 4; ++nf) {
                    int col = n0 + wc * 64 + nf * 16 + lq;
                    float v = acc[mf][nf][r];
                    if (MODE == 0) {
                        if (bias) v += bias[col];
                        ((float*)Cv)[(size_t)bz * cBatch + (size_t)grow * ldc + col] = v;
                    } else {
                        u16 bv = (grow < 98) ? f2bf(v) : (u16)0;
                        if (col < 256) {
                            int hh = col >> 5, d = col & 31;
                            Kb[((size_t)(bz * 8 + hh) * 112 + grow) * 32 + d] = bv;
                        } else {
                            int cc = col - 256;
                            int hh = cc >> 5, d = cc & 31;
                            Vtb[((size_t)(bz * 8 + hh) * 32 + d) * 112 + grow] = bv;
                        }
                    }
                }
            }
        }
    }
}

// ---------------------------------------------------------------------------
// Combined Q projection (both branches, one dispatch): per-row pointer select.
// Rows 0..3135 from x0b, 3136..3919 from x1b. Out: Yq bf16 [8][3920][256].
// ---------------------------------------------------------------------------
__global__ __launch_bounds__(256) void qproj_kernel(
    const u16* __restrict__ x0b, const u16* __restrict__ x1b,
    const u16* __restrict__ Bw, u16* __restrict__ Yq)
{
    __shared__ u16 lsA[128 * 64];
    __shared__ u16 lsB[128 * 64];
    int tid = threadIdx.x;
    int w = tid >> 6, l = tid & 63, g = l >> 4, lq = l & 15;
    int wr = w >> 1, wc = w & 1;
    int m0 = blockIdx.y * 128, n0 = blockIdx.x * 128;
    int bz = blockIdx.z;

    const u16* aptr[4];
    long boff[4];
    #pragma unroll
    for (int i = 0; i < 4; ++i) {
        int p = (w * 4 + i) * 64 + l;
        int r = p >> 3, cp = p & 7;
        int ar = m0 + r; ar = ar < 3920 ? ar : 3919;
        const u16* base = (ar < 3136)
            ? x0b + ((size_t)bz * 3136 + ar) * 256
            : x1b + ((size_t)bz * 784 + (ar - 3136)) * 256;
        aptr[i] = base + ((cp ^ (r & 7)) << 3);
        boff[i] = (long)(n0 + r) * 256 + ((cp ^ (r & 7)) << 3);
    }
    f4 acc[4][4];
    #pragma unroll
    for (int i = 0; i < 4; ++i)
        #pragma unroll
        for (int j = 0; j < 4; ++j) acc[i][j] = (f4){0.f, 0.f, 0.f, 0.f};

    for (int k0 = 0; k0 < 256; k0 += 64) {
        __syncthreads();
        #pragma unroll
        for (int i = 0; i < 4; ++i)
            GLDS16(aptr[i] + k0, &lsA[(w * 4 + i) * 512]);
        #pragma unroll
        for (int i = 0; i < 4; ++i)
            GLDS16(Bw + boff[i] + k0, &lsB[(w * 4 + i) * 512]);
        __syncthreads();
        #pragma unroll
        for (int kk = 0; kk < 2; ++kk) {
            s8v af[4], bf[4];
            #pragma unroll
            for (int mf = 0; mf < 4; ++mf) {
                int row = wr * 64 + mf * 16 + lq;
                int ph = (kk * 4 + g) ^ (row & 7);
                af[mf] = *(const s8v*)&lsA[row * 64 + ph * 8];
            }
            #pragma unroll
            for (int nf = 0; nf < 4; ++nf) {
                int row = wc * 64 + nf * 16 + lq;
                int ph = (kk * 4 + g) ^ (row & 7);
                bf[nf] = *(const s8v*)&lsB[row * 64 + ph * 8];
            }
            #pragma unroll
            for (int mf = 0; mf < 4; ++mf)
                #pragma unroll
                for (int nf = 0; nf < 4; ++nf)
                    acc[mf][nf] = __builtin_amdgcn_mfma_f32_16x16x32_bf16(
                        af[mf], bf[nf], acc[mf][nf], 0, 0, 0);
        }
    }
    #pragma unroll
    for (int mf = 0; mf < 4; ++mf) {
        #pragma unroll
        for (int r = 0; r < 4; ++r) {
            int grow = m0 + wr * 64 + mf * 16 + g * 4 + r;
            if (grow < 3920) {
                #pragma unroll
                for (int nf = 0; nf < 4; ++nf) {
                    int col = n0 + wc * 64 + nf * 16 + lq;
                    Yq[((size_t)bz * 3920 + grow) * 256 + col] = f2bf(acc[mf][nf][r]);
                }
            }
        }
    }
}

// ---------------------------------------------------------------------------
// Combined conv (both branches) as MFMA GEMM, split-K into slice buffers.
// z<32: branch0 slice z (Ksl=512, Kc=16384); z>=32: branch1 slice z-32
// (Ksl=512, Kc=4096). M=392, N=256.
// ---------------------------------------------------------------------------
__global__ __launch_bounds__(256) void conv2_kernel(
    const u16* __restrict__ x0b, const u16* __restrict__ x1b,
    const u16* __restrict__ Wc0, const u16* __restrict__ Wc1,
    float* __restrict__ xr0, float* __restrict__ xr1)
{
    __shared__ u16 lsA[128 * 64];
    __shared__ u16 lsB[128 * 64];
    int tid = threadIdx.x;
    int w = tid >> 6, l = tid & 63, g = l >> 4, lq = l & 15;
    int wr = w >> 1, wc = w & 1;
    int m0 = blockIdx.y * 128, n0 = blockIdx.x * 128;
    int z = blockIdx.z;

    const u16* Xb; const u16* Wc; float* Co;
    int Npix, Wimg, lgs, Kc, zz;
    if (z < 32) { Xb = x0b; Wc = Wc0; Co = xr0; Npix = 3136; Wimg = 56; lgs = 3; Kc = 16384; zz = z; }
    else        { Xb = x1b; Wc = Wc1; Co = xr1; Npix = 784;  Wimg = 28; lgs = 2; Kc = 4096;  zz = z - 32; }
    int s = 1 << lgs;

    long aoff[4], boff[4];
    #pragma unroll
    for (int i = 0; i < 4; ++i) {
        int p = (w * 4 + i) * 64 + l;
        int r = p >> 3, cp = p & 7;
        int rr = m0 + r; rr = rr < 392 ? rr : 391;
        int bb = rr / 49, pp = rr % 49;
        int ph = pp / 7, pw = pp % 7;
        aoff[i] = ((long)bb * Npix + (long)(ph * Wimg + pw) * s) * 256 + ((cp ^ (r & 7)) << 3);
        boff[i] = (long)(n0 + r) * Kc + ((cp ^ (r & 7)) << 3);
    }
    f4 acc[4][4];
    #pragma unroll
    for (int i = 0; i < 4; ++i)
        #pragma unroll
        for (int j = 0; j < 4; ++j) acc[i][j] = (f4){0.f, 0.f, 0.f, 0.f};

    int kbase = zz * 512;
    for (int ko = 0; ko < 512; ko += 64) {
        int k0 = kbase + ko;
        int khw = k0 >> 8;
        int kh = khw >> lgs, kw = khw & (s - 1);
        long adelta = (long)(kh * Wimg + kw) * 256 + (k0 & 255);
        __syncthreads();
        #pragma unroll
        for (int i = 0; i < 4; ++i)
            GLDS16(Xb + aoff[i] + adelta, &lsA[(w * 4 + i) * 512]);
        #pragma unroll
        for (int i = 0; i < 4; ++i)
            GLDS16(Wc + boff[i] + k0, &lsB[(w * 4 + i) * 512]);
        __syncthreads();
        #pragma unroll
        for (int kk = 0; kk < 2; ++kk) {
            s8v af[4], bf[4];
            #pragma unroll
            for (int mf = 0; mf < 4; ++mf) {
                int row = wr * 64 + mf * 16 + lq;
                int ph2 = (kk * 4 + g) ^ (row & 7);
                af[mf] = *(const s8v*)&lsA[row * 64 + ph2 * 8];
            }
            #pragma unroll
            for (int nf = 0; nf < 4; ++nf) {
                int row = wc * 64 + nf * 16 + lq;
                int ph2 = (kk * 4 + g) ^ (row & 7);
                bf[nf] = *(const s8v*)&lsB[row * 64 + ph2 * 8];
            }
            #pragma unroll
            for (int mf = 0; mf < 4; ++mf)
                #pragma unroll
                for (int nf = 0; nf < 4; ++nf)
                    acc[mf][nf] = __builtin_amdgcn_mfma_f32_16x16x32_bf16(
                        af[mf], bf[nf], acc[mf][nf], 0, 0, 0);
        }
    }
    float* Cb = Co + (size_t)zz * 392 * 256;
    #pragma unroll
    for (int mf = 0; mf < 4; ++mf) {
        #pragma unroll
        for (int r = 0; r < 4; ++r) {
            int grow = m0 + wr * 64 + mf * 16 + g * 4 + r;
            if (grow < 392) {
                #pragma unroll
                for (int nf = 0; nf < 4; ++nf) {
                    int col = n0 + wc * 64 + nf * 16 + lq;
                    Cb[(size_t)grow * 256 + col] = acc[mf][nf][r];
                }
            }
        }
    }
}

// ---------------------------------------------------------------------------
// LayerNorm: sum conv slices + conv bias, normalize, write bf16.
// ---------------------------------------------------------------------------
__global__ __launch_bounds__(256) void ln_kernel(
    const float* __restrict__ xr0, const float* __restrict__ xr1,
    const float* __restrict__ srb0, const float* __restrict__ srb1,
    const float* __restrict__ n0w, const float* __restrict__ n0b,
    const float* __restrict__ n1w, const float* __restrict__ n1b,
    u16* __restrict__ lnb)
{
    int row = blockIdx.x;            // 0..783
    int b = row / 98, j = row % 98;
    int c = threadIdx.x;
    const float* src; int sidx, ns;
    const float *bs, *nw, *nb;
    if (j < 49) { src = xr0; sidx = b * 49 + j;       ns = 32; bs = srb0; nw = n0w; nb = n0b; }
    else        { src = xr1; sidx = b * 49 + (j - 49); ns = 8; bs = srb1; nw = n1w; nb = n1b; }
    float v = bs[c];
    for (int sl = 0; sl < ns; ++sl) v += src[(size_t)sl * 100352 + (size_t)sidx * 256 + c];
    __shared__ float red[8];
    float sumv = v;
    #pragma unroll
    for (int off = 32; off; off >>= 1) sumv += __shfl_down(sumv, off, 64);
    int wid = c >> 6, lane = c & 63;
    if (lane == 0) red[wid] = sumv;
    __syncthreads();
    float mu = (red[0] + red[1] + red[2] + red[3]) * (1.0f / 256.0f);
    float dv = v - mu;
    float s2 = dv * dv;
    #pragma unroll
    for (int off = 32; off; off >>= 1) s2 += __shfl_down(s2, off, 64);
    if (lane == 0) red[4 + wid] = s2;
    __syncthreads();
    float var = (red[4] + red[5] + red[6] + red[7]) * (1.0f / 256.0f);
    float rr = rsqrtf(var + 1e-5f);
    lnb[(size_t)row * 256 + c] = f2bf(dv * rr * nw[c] + nb[c]);
}

// ---------------------------------------------------------------------------
// MFMA attention — all-bf16 I/O, XOR-swizzled LDS.
// Block = (b,h) x 64 queries (4 waves x 16q). Kb[bh][112][32], Vtb[bh][32][112].
// ---------------------------------------------------------------------------
#define SCALE_F 0.1767766952966369f
__global__ __launch_bounds__(256) void attn_kernel(
    const u16* __restrict__ Yq, const u16* __restrict__ Kb,
    const u16* __restrict__ Vtb, u16* __restrict__ Xc)
{
    __shared__ u16 Qs[64 * 32];
    __shared__ u16 Ks[112 * 32];
    __shared__ u16 VtS[64 * 64];       // R = d + 32*(key>=64), col = key%64
    __shared__ u16 Ps[4][16 * 128];
    __shared__ float Ot[4][16 * 36];
    int tid = threadIdx.x;
    int w = tid >> 6, l = tid & 63, g = l >> 4, lq = l & 15;
    int bh = blockIdx.y, b = bh >> 3, h = bh & 7;
    int n0 = blockIdx.x * 64;

    {   // Q: 64 rows x 32 bf16, one 16B chunk per thread, swizzled
        int r = tid >> 2, c = tid & 3;
        int qr = n0 + r; qr = qr < 3920 ? qr : 3919;
        s8v qv = *(const s8v*)(Yq + ((size_t)b * 3920 + qr) * 256 + h * 32 + c * 8);
        *(s8v*)&Qs[r * 32 + ((c ^ (r & 3)) * 8)] = qv;
    }
    // K: 112 rows x 32 bf16 (rows >=98 are zero in Kb)
    #pragma unroll
    for (int i = 0; i < 2; ++i) {
        int u = tid + i * 256;
        int row = u >> 2, c = u & 3;
        if (row < 112) {
            s8v kv = *(const s8v*)(Kb + ((size_t)bh * 112 + row) * 32 + c * 8);
            *(s8v*)&Ks[row * 32 + ((c ^ (row & 3)) * 8)] = kv;
        }
    }
    // V^T: VtS[64][64]; source Vtb[bh][d][112] (cols >=98 zero)
    #pragma unroll
    for (int i = 0; i < 2; ++i) {
        int u = tid + i * 256;
        int R = u >> 3, c3 = u & 7;
        int d = R & 31, j = (R >> 5) * 64 + c3 * 8;
        s8v vv;
        if (j < 112) vv = *(const s8v*)(Vtb + ((size_t)bh * 32 + d) * 112 + j);
        else         vv = (s8v){0, 0, 0, 0, 0, 0, 0, 0};
        *(s8v*)&VtS[R * 64 + ((c3 ^ (R & 7)) * 8)] = vv;
    }
    __syncthreads();

    // QK^T (swapped): S^T[key][q]
    int qrow = w * 16 + lq;
    s8v qf = *(const s8v*)&Qs[qrow * 32 + ((g ^ (lq & 3)) * 8)];
    f4 sacc[7];
    #pragma unroll
    for (int f = 0; f < 7; ++f) {
        int krow = f * 16 + lq;
        s8v kf = *(const s8v*)&Ks[krow * 32 + ((g ^ (lq & 3)) * 8)];
        f4 zz = (f4){0.f, 0.f, 0.f, 0.f};
        sacc[f] = __builtin_amdgcn_mfma_f32_16x16x32_bf16(kf, qf, zz, 0, 0, 0);
    }
    // softmax over keys
    float pm = -1e30f;
    float sv[7][4];
    #pragma unroll
    for (int f = 0; f < 7; ++f)
        #pragma unroll
        for (int r = 0; r < 4; ++r) {
            int key = f * 16 + g * 4 + r;
            float v = sacc[f][r] * SCALE_F;
            if (key >= 98) v = -1e30f;
            sv[f][r] = v;
            pm = fmaxf(pm, v);
        }
    pm = fmaxf(pm, __shfl_xor(pm, 16));
    pm = fmaxf(pm, __shfl_xor(pm, 32));
    float sum = 0.f;
    float pv[7][4];
    #pragma unroll
    for (int f = 0; f < 7; ++f)
        #pragma unroll
        for (int r = 0; r < 4; ++r) {
            float e = __expf(sv[f][r] - pm);
            pv[f][r] = e;
            sum += e;
        }
    sum += __shfl_xor(sum, 16);
    sum += __shfl_xor(sum, 32);
    float inv = 1.0f / sum;

    // P -> LDS, swizzled; zero keys 112..127
    u16* Pw = Ps[w];
    if (l < 32) {
        int row = l >> 1;
        int gr = (14 + (l & 1)) ^ (row & 7);
        *(s8v*)&Pw[row * 128 + gr * 8] = (s8v){0, 0, 0, 0, 0, 0, 0, 0};
    }
    #pragma unroll
    for (int f = 0; f < 7; ++f)
        #pragma unroll
        for (int pr = 0; pr < 2; ++pr) {
            u32 pk = (u32)f2bf(pv[f][2 * pr] * inv) |
                     ((u32)f2bf(pv[f][2 * pr + 1] * inv) << 16);
            int k = f * 16 + g * 4 + pr * 2;
            int gr = (k >> 3) ^ (lq & 7);
            *(u32*)&Pw[lq * 128 + gr * 8 + (k & 7)] = pk;
        }

    // PV: out[q][d] = sum_key P[q][key] * V^T[d][key]
    f4 o0 = (f4){0.f, 0.f, 0.f, 0.f}, o1 = (f4){0.f, 0.f, 0.f, 0.f};
    #pragma unroll
    for (int s4 = 0; s4 < 4; ++s4) {
        int gv = s4 * 4 + g;
        s8v pa = *(const s8v*)&Pw[lq * 128 + ((gv ^ (lq & 7)) * 8)];
        int gvv = (s4 & 1) * 4 + g;
        int Rb = 32 * (s4 >> 1);
        s8v vf0 = *(const s8v*)&VtS[(Rb + lq) * 64 + ((gvv ^ (lq & 7)) * 8)];
        s8v vf1 = *(const s8v*)&VtS[(Rb + 16 + lq) * 64 + ((gvv ^ (lq & 7)) * 8)];
        o0 = __builtin_amdgcn_mfma_f32_16x16x32_bf16(pa, vf0, o0, 0, 0, 0);
        o1 = __builtin_amdgcn_mfma_f32_16x16x32_bf16(pa, vf1, o1, 0, 0, 0);
    }
    // bounce through LDS for coalesced bf16 store
    #pragma unroll
    for (int r = 0; r < 4; ++r) {
        Ot[w][(g * 4 + r) * 36 + 0 * 16 + lq] = o0[r];
        Ot[w][(g * 4 + r) * 36 + 1 * 16 + lq] = o1[r];
    }
    int qloc = l >> 2, c4 = l & 3;
    int qg = n0 + w * 16 + qloc;
    if (qg < 3920) {
        #pragma unroll
        for (int half = 0; half < 2; ++half) {
            int cc = c4 + half * 4;
            u16x4 ov;
            #pragma unroll
            for (int i = 0; i < 4; ++i) ov[i] = f2bf(Ot[w][qloc * 36 + cc * 4 + i]);
            *(u16x4*)(Xc + ((size_t)b * 3920 + qg) * 256 + h * 32 + cc * 4) = ov;
        }
    }
}

// ---------------------------------------------------------------------------
extern "C" void kernel_launch(void* const* d_in, const int* in_sizes, int n_in,
                              void* d_out, int out_size, void* d_ws, size_t ws_size,
                              hipStream_t stream)
{
    const float* x0     = (const float*)d_in[0];
    const float* x1     = (const float*)d_in[1];
    const float* q_w    = (const float*)d_in[2];
    const float* kv_w   = (const float*)d_in[3];
    const float* proj_w = (const float*)d_in[4];
    const float* proj_b = (const float*)d_in[5];
    const float* sr0_w  = (const float*)d_in[6];
    const float* sr0_b  = (const float*)d_in[7];
    const float* sr1_w  = (const float*)d_in[8];
    const float* sr1_b  = (const float*)d_in[9];
    const float* n0w    = (const float*)d_in[10];
    const float* n0b    = (const float*)d_in[11];
    const float* n1w    = (const float*)d_in[12];
    const float* n1b    = (const float*)d_in[13];
    (void)in_sizes; (void)n_in; (void)out_size; (void)ws_size;

    float* ws = (float*)d_ws;
    u16*  Yq   = (u16*)ws;                         // [8][3920][256] bf16
    u16*  XcU  = (u16*)(ws + 4014080);             // bf16 [31360][256]; overlays x0b/x1b
    u16*  x0b  = XcU;                              // [25088][256] bf16 (dead before attn)
    u16*  x1b  = XcU + 6422528;                    // [6272][256] bf16
    float* xr0 = ws + 8028160;                     // [32][392][256] fp32 slices
    float* xr1 = ws + 11239424;                    // [8][392][256]
    u16*  Kb   = (u16*)(ws + 12042240);            // [64][112][32] bf16
    u16*  Vtb  = (u16*)(ws + 12156928);            // [64][32][112] bf16
    u16*  lnb  = (u16*)(ws + 12271616);            // [784][256] bf16
    u16*  qwb  = (u16*)(ws + 12371968);            // [256][256] bf16
    u16*  kvwb = (u16*)(ws + 12404736);            // [512][256] bf16
    u16*  pwb  = (u16*)(ws + 12470272);            // [256][256] bf16
    u16*  Wc0  = (u16*)(ws + 12503040);            // [256][16384] bf16
    u16*  Wc1  = (u16*)(ws + 14600192);            // [256][4096] bf16

    // 1. fused converts + weight transposes
    prep_kernel<<<2048, 256, 0, stream>>>(
        x0, x1, q_w, kv_w, proj_w, sr0_w, sr1_w,
        x0b, x1b, qwb, kvwb, pwb, Wc0, Wc1);

    // 2. Q projection (both branches, one dispatch) -> bf16
    qproj_kernel<<<dim3(2, 31, 8), 256, 0, stream>>>(x0b, x1b, qwb, Yq);

    // 3. spatial-reduction convs (both branches, split-K slice buffers)
    conv2_kernel<<<dim3(2, 4, 40), 256, 0, stream>>>(x0b, x1b, Wc0, Wc1, xr0, xr1);

    // 4. layernorm (+conv bias, slice reduce) -> bf16
    ln_kernel<<<784, 256, 0, stream>>>(xr0, xr1, sr0_b, sr1_b, n0w, n0b, n1w, n1b, lnb);

    // 5. KV projection -> scatter to Kb / Vtb (zero-fills rows/cols 98..111)
    gemm_kernel<2><<<dim3(4, 1, 8), 256, 0, stream>>>(
        lnb, 98L * 256, 98, kvwb, 256, nullptr, 0, 0, nullptr, Kb, Vtb);

    // 6. attention -> Xc bf16
    attn_kernel<<<dim3(62, 64), 256, 0, stream>>>(Yq, Kb, Vtb, XcU);

    // 7. output projection (+bias) -> d_out fp32
    gemm_kernel<0><<<dim3(2, 245, 1), 256, 0, stream>>>(
        XcU, 0, 31360, pwb, 256, (float*)d_out, 0, 256, proj_b, nullptr, nullptr);
}